// Round 1
// baseline (148.439 us; speedup 1.0000x reference)
//
#include <hip/hip_runtime.h>
#include <math.h>

#define BB 32
#define NN 512
#define NFEAT 128
#define NHID 8
#define NHEADS 8
#define LALPHA 0.2f

__device__ __forceinline__ float lrelu(float x) { return x >= 0.f ? x : LALPHA * x; }
__device__ __forceinline__ float elu1(float x)  { return x > 0.f ? x : __expf(x) - 1.f; }

// K1: Wh[b,h,n,:] = neighbor_feats[b,n,:] @ Ws[h];  s1 = Wh@a[:8], s2 = Wh@a[8:]
__global__ __launch_bounds__(256) void k1_wh(
        const float* __restrict__ nf, const float* __restrict__ Ws,
        const float* __restrict__ As, float* __restrict__ Wh,
        float* __restrict__ s1, float* __restrict__ s2)
{
    __shared__ float WsL[NFEAT * NHID];   // 4 KB
    __shared__ float aL[16];
    const int bh = blockIdx.x;            // b*8 + h
    const int b = bh >> 3, h = bh & 7;
    const int t = threadIdx.x;

    ((float4*)WsL)[t] = ((const float4*)(Ws + (size_t)h * NFEAT * NHID))[t]; // 1024 floats
    if (t < 16) aL[t] = As[h * 16 + t];
    __syncthreads();

    for (int r = 0; r < 2; ++r) {
        const int n = r * 256 + t;
        const float4* row = (const float4*)(nf + ((size_t)b * NN + n) * NFEAT);
        float acc[NHID];
        #pragma unroll
        for (int d = 0; d < NHID; ++d) acc[d] = 0.f;
        #pragma unroll 8
        for (int f4 = 0; f4 < NFEAT / 4; ++f4) {
            float4 v = row[f4];
            const float* w0 = &WsL[(f4 * 4 + 0) * NHID];
            const float* w1 = &WsL[(f4 * 4 + 1) * NHID];
            const float* w2 = &WsL[(f4 * 4 + 2) * NHID];
            const float* w3 = &WsL[(f4 * 4 + 3) * NHID];
            #pragma unroll
            for (int d = 0; d < NHID; ++d)
                acc[d] += v.x * w0[d] + v.y * w1[d] + v.z * w2[d] + v.w * w3[d];
        }
        float a1 = 0.f, a2 = 0.f;
        #pragma unroll
        for (int d = 0; d < NHID; ++d) { a1 += acc[d] * aL[d]; a2 += acc[d] * aL[8 + d]; }
        float* dst = Wh + ((size_t)bh * NN + n) * NHID;
        ((float4*)dst)[0] = make_float4(acc[0], acc[1], acc[2], acc[3]);
        ((float4*)dst)[1] = make_float4(acc[4], acc[5], acc[6], acc[7]);
        s1[bh * NN + n] = a1;
        s2[bh * NN + n] = a2;
    }
}

// K2: layer-1 attention per (b,h). denom[j] = sum_i exp(lrelu(s1[i]+s2[j]));
// x[b,i,h*8+d] = elu( sum_j exp(lrelu(s1[i]+s2[j])) * Wh[j,d]/denom[j] )
__global__ __launch_bounds__(256) void k2_attn1(
        const float* __restrict__ Wh, const float* __restrict__ s1g,
        const float* __restrict__ s2g, float* __restrict__ x)
{
    __shared__ float s1L[NN], s2L[NN];
    __shared__ float whn[NN * NHID];      // 16 KB
    const int bh = blockIdx.x;
    const int b = bh >> 3, h = bh & 7;
    const int t = threadIdx.x;

    s1L[t]       = s1g[bh * NN + t];
    s1L[t + 256] = s1g[bh * NN + t + 256];
    s2L[t]       = s2g[bh * NN + t];
    s2L[t + 256] = s2g[bh * NN + t + 256];
    {
        const float4* src = (const float4*)(Wh + (size_t)bh * NN * NHID);
        float4* dst = (float4*)whn;       // 1024 float4s
        dst[t]       = src[t];
        dst[t + 256] = src[t + 256];
        dst[t + 512] = src[t + 512];
        dst[t + 768] = src[t + 768];
    }
    __syncthreads();

    // phase 1: column denominators, pre-scale whn rows
    for (int c = 0; c < 2; ++c) {
        const int j = c * 256 + t;
        const float s2j = s2L[j];
        float den = 0.f;
        #pragma unroll 4
        for (int i = 0; i < NN; ++i) {
            float e = s1L[i] + s2j;
            e = e >= 0.f ? e : LALPHA * e;
            den += __expf(e);
        }
        const float inv = 1.f / den;
        #pragma unroll
        for (int d = 0; d < NHID; ++d) whn[j * NHID + d] *= inv;
    }
    __syncthreads();

    // phase 2: weighted rows
    for (int r = 0; r < 2; ++r) {
        const int i = r * 256 + t;
        const float s1i = s1L[i];
        float acc[NHID];
        #pragma unroll
        for (int d = 0; d < NHID; ++d) acc[d] = 0.f;
        #pragma unroll 2
        for (int j = 0; j < NN; ++j) {
            float e = s1i + s2L[j];
            e = e >= 0.f ? e : LALPHA * e;
            const float w = __expf(e);
            const float* wr = &whn[j * NHID];
            #pragma unroll
            for (int d = 0; d < NHID; ++d) acc[d] += w * wr[d];
        }
        float* xp = x + ((size_t)(b * NN + i)) * (NHEADS * NHID) + h * NHID;
        ((float4*)xp)[0] = make_float4(elu1(acc[0]), elu1(acc[1]), elu1(acc[2]), elu1(acc[3]));
        ((float4*)xp)[1] = make_float4(elu1(acc[4]), elu1(acc[5]), elu1(acc[6]), elu1(acc[7]));
    }
}

// K3: Wh2[b,n,:] = x[b,n,:] @ W_out; s1_2, s2_2 from a_out
__global__ __launch_bounds__(256) void k3_wh2(
        const float* __restrict__ x, const float* __restrict__ Wout,
        const float* __restrict__ aout, float* __restrict__ Wh2,
        float* __restrict__ s1g, float* __restrict__ s2g)
{
    __shared__ float WL[64 * NHID];       // 2 KB
    __shared__ float aL[16];
    const int t = threadIdx.x;
    if (t < 128) ((float4*)WL)[t] = ((const float4*)Wout)[t];
    if (t < 16) aL[t] = aout[t];
    __syncthreads();

    const int idx = blockIdx.x * 256 + t; // b*NN + n
    const float4* row = (const float4*)(x + (size_t)idx * 64);
    float acc[NHID];
    #pragma unroll
    for (int d = 0; d < NHID; ++d) acc[d] = 0.f;
    #pragma unroll 4
    for (int k4 = 0; k4 < 16; ++k4) {
        float4 v = row[k4];
        const float* w0 = &WL[(k4 * 4 + 0) * NHID];
        const float* w1 = &WL[(k4 * 4 + 1) * NHID];
        const float* w2 = &WL[(k4 * 4 + 2) * NHID];
        const float* w3 = &WL[(k4 * 4 + 3) * NHID];
        #pragma unroll
        for (int d = 0; d < NHID; ++d)
            acc[d] += v.x * w0[d] + v.y * w1[d] + v.z * w2[d] + v.w * w3[d];
    }
    float a1 = 0.f, a2 = 0.f;
    #pragma unroll
    for (int d = 0; d < NHID; ++d) { a1 += acc[d] * aL[d]; a2 += acc[d] * aL[8 + d]; }
    float* dst = Wh2 + (size_t)idx * NHID;
    ((float4*)dst)[0] = make_float4(acc[0], acc[1], acc[2], acc[3]);
    ((float4*)dst)[1] = make_float4(acc[4], acc[5], acc[6], acc[7]);
    s1g[idx] = a1;
    s2g[idx] = a2;
}

// K4: layer-2 attention, only output row i=0 needed. gat[b,d] = elu(h0[d])
__global__ __launch_bounds__(256) void k4_attn2(
        const float* __restrict__ Wh2, const float* __restrict__ s1g,
        const float* __restrict__ s2g, float* __restrict__ gat)
{
    __shared__ float s1L[NN], s2L[NN];
    __shared__ float whL[NN * NHID];      // 16 KB
    __shared__ float red[256 * NHID];     // 8 KB
    const int b = blockIdx.x;
    const int t = threadIdx.x;

    s1L[t]       = s1g[b * NN + t];
    s1L[t + 256] = s1g[b * NN + t + 256];
    s2L[t]       = s2g[b * NN + t];
    s2L[t + 256] = s2g[b * NN + t + 256];
    {
        const float4* src = (const float4*)(Wh2 + (size_t)b * NN * NHID);
        float4* dst = (float4*)whL;
        dst[t]       = src[t];
        dst[t + 256] = src[t + 256];
        dst[t + 512] = src[t + 512];
        dst[t + 768] = src[t + 768];
    }
    __syncthreads();

    float acc[NHID];
    #pragma unroll
    for (int d = 0; d < NHID; ++d) acc[d] = 0.f;
    const float s10 = s1L[0];
    for (int c = 0; c < 2; ++c) {
        const int j = c * 256 + t;
        const float s2j = s2L[j];
        float den = 0.f;
        #pragma unroll 4
        for (int i = 0; i < NN; ++i) {
            float e = s1L[i] + s2j;
            e = e >= 0.f ? e : LALPHA * e;
            den += __expf(e);
        }
        float e0 = s10 + s2j;
        e0 = e0 >= 0.f ? e0 : LALPHA * e0;
        const float w = __expf(e0) / den;
        const float* wr = &whL[j * NHID];
        #pragma unroll
        for (int d = 0; d < NHID; ++d) acc[d] += w * wr[d];
    }
    #pragma unroll
    for (int d = 0; d < NHID; ++d) red[t * NHID + d] = acc[d];
    __syncthreads();
    for (int s = 128; s > 0; s >>= 1) {
        if (t < s) {
            #pragma unroll
            for (int d = 0; d < NHID; ++d)
                red[t * NHID + d] += red[(t + s) * NHID + d];
        }
        __syncthreads();
    }
    if (t < NHID) gat[b * NHID + t] = elu1(red[t]);
}

// K5: z = [feats, gat] @ lin1_w.T + b; prelu; bn-affine; out = z @ lin2_w.T + b
__global__ __launch_bounds__(256) void k5_head(
        const float* __restrict__ feats, const float* __restrict__ gat,
        const float* __restrict__ l1w, const float* __restrict__ l1b,
        const float* __restrict__ pa, const float* __restrict__ gma,
        const float* __restrict__ bta, const float* __restrict__ l2w,
        const float* __restrict__ l2b, float* __restrict__ out)
{
    __shared__ float zL[BB * NHID];
    const int t = threadIdx.x;            // 256 = 32*8
    const int b = t >> 3, d = t & 7;
    const float* w = l1w + d * (NFEAT + NHID);
    float z = l1b[d];
    for (int k = 0; k < NFEAT; ++k) z += feats[b * NFEAT + k] * w[k];
    #pragma unroll
    for (int k = 0; k < NHID; ++k) z += gat[b * NHID + k] * w[NFEAT + k];
    const float a = pa[0];
    z = z >= 0.f ? z : a * z;
    z = z * (1.f / sqrtf(1.f + 1e-5f)) * gma[d] + bta[d];
    zL[t] = z;
    __syncthreads();
    if (t < BB) {
        float o = l2b[0];
        #pragma unroll
        for (int d2 = 0; d2 < NHID; ++d2) o += zL[t * NHID + d2] * l2w[d2];
        out[t] = o;
    }
}

extern "C" void kernel_launch(void* const* d_in, const int* in_sizes, int n_in,
                              void* d_out, int out_size, void* d_ws, size_t ws_size,
                              hipStream_t stream) {
    const float* feats = (const float*)d_in[0];
    const float* nf    = (const float*)d_in[1];
    const float* Ws    = (const float*)d_in[2];
    const float* As    = (const float*)d_in[3];
    const float* Wout  = (const float*)d_in[4];
    const float* aout  = (const float*)d_in[5];
    const float* l1w   = (const float*)d_in[6];
    const float* l1b   = (const float*)d_in[7];
    const float* pa    = (const float*)d_in[8];
    const float* gma   = (const float*)d_in[9];
    const float* bta   = (const float*)d_in[10];
    const float* l2w   = (const float*)d_in[11];
    const float* l2b   = (const float*)d_in[12];
    float* out = (float*)d_out;

    float* ws  = (float*)d_ws;
    float* Wh  = ws;                                   // 32*8*512*8 = 1048576
    float* s1  = Wh  + (size_t)BB * NHEADS * NN * NHID; // 131072
    float* s2  = s1  + (size_t)BB * NHEADS * NN;        // 131072
    float* x   = s2  + (size_t)BB * NHEADS * NN;        // 32*512*64 = 1048576
    float* Wh2 = x   + (size_t)BB * NN * NHEADS * NHID; // 131072
    float* s12 = Wh2 + (size_t)BB * NN * NHID;          // 16384
    float* s22 = s12 + (size_t)BB * NN;                 // 16384
    float* gat = s22 + (size_t)BB * NN;                 // 256

    k1_wh   <<<BB * NHEADS, 256, 0, stream>>>(nf, Ws, As, Wh, s1, s2);
    k2_attn1<<<BB * NHEADS, 256, 0, stream>>>(Wh, s1, s2, x);
    k3_wh2  <<<BB * NN / 256, 256, 0, stream>>>(x, Wout, aout, Wh2, s12, s22);
    k4_attn2<<<BB, 256, 0, stream>>>(Wh2, s12, s22, gat);
    k5_head <<<1, 256, 0, stream>>>(feats, gat, l1w, l1b, pa, gma, bta, l2w, l2b, out);
}

// Round 2
// 80.031 us; speedup vs baseline: 1.8548x; 1.8548x over previous
//
#include <hip/hip_runtime.h>
#include <math.h>

#define BB 32
#define NN 512
#define NFEAT 128
#define NHID 8
#define NHEADS 8
#define LALPHA 0.2f

__device__ __forceinline__ float elu1(float x)  { return x > 0.f ? x : __expf(x) - 1.f; }

// first index k in [0,512] with a[k] >= v (a ascending)
__device__ __forceinline__ int lb512(const float* a, float v) {
    int lo = 0, hi = NN;
    while (lo < hi) {
        int m = (lo + hi) >> 1;
        if (a[m] < v) lo = m + 1; else hi = m;
    }
    return lo;
}

// K1: Wh[b,h,n,:] = neighbor_feats[b,n,:] @ Ws[h];  s1 = Wh@a[:8], s2 = Wh@a[8:]
__global__ __launch_bounds__(256) void k1_wh(
        const float* __restrict__ nf, const float* __restrict__ Ws,
        const float* __restrict__ As, float* __restrict__ Wh,
        float* __restrict__ s1, float* __restrict__ s2)
{
    __shared__ __align__(16) float WsL[NFEAT * NHID];   // 4 KB
    __shared__ float aL[16];
    const int bh = blockIdx.x;            // b*8 + h
    const int b = bh >> 3, h = bh & 7;
    const int t = threadIdx.x;

    ((float4*)WsL)[t] = ((const float4*)(Ws + (size_t)h * NFEAT * NHID))[t];
    if (t < 16) aL[t] = As[h * 16 + t];
    __syncthreads();

    for (int r = 0; r < 2; ++r) {
        const int n = r * 256 + t;
        const float4* row = (const float4*)(nf + ((size_t)b * NN + n) * NFEAT);
        float acc[NHID];
        #pragma unroll
        for (int d = 0; d < NHID; ++d) acc[d] = 0.f;
        #pragma unroll 8
        for (int f4 = 0; f4 < NFEAT / 4; ++f4) {
            float4 v = row[f4];
            const float* w0 = &WsL[(f4 * 4 + 0) * NHID];
            const float* w1 = &WsL[(f4 * 4 + 1) * NHID];
            const float* w2 = &WsL[(f4 * 4 + 2) * NHID];
            const float* w3 = &WsL[(f4 * 4 + 3) * NHID];
            #pragma unroll
            for (int d = 0; d < NHID; ++d)
                acc[d] += v.x * w0[d] + v.y * w1[d] + v.z * w2[d] + v.w * w3[d];
        }
        float a1 = 0.f, a2 = 0.f;
        #pragma unroll
        for (int d = 0; d < NHID; ++d) { a1 += acc[d] * aL[d]; a2 += acc[d] * aL[8 + d]; }
        float* dst = Wh + ((size_t)bh * NN + n) * NHID;
        ((float4*)dst)[0] = make_float4(acc[0], acc[1], acc[2], acc[3]);
        ((float4*)dst)[1] = make_float4(acc[4], acc[5], acc[6], acc[7]);
        s1[bh * NN + n] = a1;
        s2[bh * NN + n] = a2;
    }
}

// K2: factorized layer-1 attention. exp(lrelu(s1+s2)) = [s1+s2>=0] e^s1 e^s2 + [<0] e^.2s1 e^.2s2
// den[j] via sorted-s1 prefix sums + binary search; rows via sorted-s2 prefix sums of p2*Wh/den.
__global__ __launch_bounds__(512) void k2_attn1(
        const float* __restrict__ Wh, const float* __restrict__ s1g,
        const float* __restrict__ s2g, float* __restrict__ x)
{
    __shared__ __align__(16) float s1L[NN];
    __shared__ __align__(16) float s2L[NN];
    __shared__ float s1s[NN];
    __shared__ float s2s[NN];
    __shared__ int   idx2[NN];
    __shared__ float prefP[NN], prefQ[NN];
    __shared__ float den[NN];
    __shared__ __align__(16) float PP[NN][NHID];     // 16 KB
    __shared__ __align__(16) float QQ[NN][NHID];     // 16 KB
    __shared__ __align__(16) float CTP[64][NHID];
    __shared__ __align__(16) float CTQ[64][NHID];

    const int bh = blockIdx.x, b = bh >> 3, h = bh & 7;
    const int t = threadIdx.x;

    s1L[t] = s1g[bh * NN + t];
    s2L[t] = s2g[bh * NN + t];
    __syncthreads();

    const float v1 = s1L[t], v2 = s2L[t];

    // rank-count sort (stable via index tie-break) of both s1 and s2 in one pass
    int r1 = 0, r2 = 0;
    {
        const float4* a4 = (const float4*)s1L;
        const float4* b4 = (const float4*)s2L;
        for (int k = 0; k < NN / 4; ++k) {
            float4 u1 = a4[k], u2 = b4[k];
            const int i0 = k * 4;
            r1 += (u1.x < v1) || (u1.x == v1 && (i0 + 0) < t);
            r1 += (u1.y < v1) || (u1.y == v1 && (i0 + 1) < t);
            r1 += (u1.z < v1) || (u1.z == v1 && (i0 + 2) < t);
            r1 += (u1.w < v1) || (u1.w == v1 && (i0 + 3) < t);
            r2 += (u2.x < v2) || (u2.x == v2 && (i0 + 0) < t);
            r2 += (u2.y < v2) || (u2.y == v2 && (i0 + 1) < t);
            r2 += (u2.z < v2) || (u2.z == v2 && (i0 + 2) < t);
            r2 += (u2.w < v2) || (u2.w == v2 && (i0 + 3) < t);
        }
    }
    s1s[r1] = v1;           // different arrays than the ones being read above
    s2s[r2] = v2;
    idx2[r2] = t;
    __syncthreads();

    // inclusive Hillis-Steele scans of exp over sorted s1
    prefP[t] = __expf(s1s[t]);
    prefQ[t] = __expf(0.2f * s1s[t]);
    __syncthreads();
    for (int s = 1; s < NN; s <<= 1) {
        float ap = prefP[t], aq = prefQ[t];
        float bp = 0.f, bq = 0.f;
        if (t >= s) { bp = prefP[t - s]; bq = prefQ[t - s]; }
        __syncthreads();
        prefP[t] = ap + bp;
        prefQ[t] = aq + bq;
        __syncthreads();
    }

    // den for original column j = t
    {
        const float TP = prefP[NN - 1];
        const int k = lb512(s1s, -v2);
        const float sp = TP - (k > 0 ? prefP[k - 1] : 0.f);
        const float sq = (k > 0 ? prefQ[k - 1] : 0.f);
        den[t] = __expf(v2) * sp + __expf(0.2f * v2) * sq;
    }
    __syncthreads();

    // payload at sorted s2 position t: p2*Wh/den, q2*Wh/den
    {
        const int j = idx2[t];
        const float key = s2s[t];
        const float invd = 1.f / den[j];
        const float4* whp = (const float4*)(Wh + ((size_t)bh * NN + j) * NHID);
        const float4 w0 = whp[0], w1 = whp[1];
        const float pw = __expf(key) * invd;
        const float qw = __expf(0.2f * key) * invd;
        float4* pp = (float4*)&PP[t][0];
        float4* qq = (float4*)&QQ[t][0];
        pp[0] = make_float4(pw * w0.x, pw * w0.y, pw * w0.z, pw * w0.w);
        pp[1] = make_float4(pw * w1.x, pw * w1.y, pw * w1.z, pw * w1.w);
        qq[0] = make_float4(qw * w0.x, qw * w0.y, qw * w0.z, qw * w0.w);
        qq[1] = make_float4(qw * w1.x, qw * w1.y, qw * w1.z, qw * w1.w);
    }
    __syncthreads();

    // inclusive scans of PP/QQ along sorted position, per dim
    {
        const int d = t & 7, p = t >> 3;     // p in [0,64)
        const int r0 = p * 8;
        float runP = 0.f, runQ = 0.f;
        #pragma unroll
        for (int s = 0; s < 8; ++s) {
            runP += PP[r0 + s][d]; PP[r0 + s][d] = runP;
            runQ += QQ[r0 + s][d]; QQ[r0 + s][d] = runQ;
        }
        CTP[p][d] = runP;
        CTQ[p][d] = runQ;
        __syncthreads();
        for (int s = 1; s < 64; s <<= 1) {
            float ap = CTP[p][d], aq = CTQ[p][d];
            float bp = 0.f, bq = 0.f;
            if (p >= s) { bp = CTP[p - s][d]; bq = CTQ[p - s][d]; }
            __syncthreads();
            CTP[p][d] = ap + bp;
            CTQ[p][d] = aq + bq;
            __syncthreads();
        }
        const float offP = p > 0 ? CTP[p - 1][d] : 0.f;
        const float offQ = p > 0 ? CTQ[p - 1][d] : 0.f;
        #pragma unroll
        for (int s = 0; s < 8; ++s) {
            PP[r0 + s][d] += offP;
            QQ[r0 + s][d] += offQ;
        }
    }
    __syncthreads();

    // row i = t: h'[i,d] = p1*(TPP[d]-prefPP[k-1][d]) + q1*prefQQ[k-1][d]
    {
        const float p1 = __expf(v1), q1 = __expf(0.2f * v1);
        const int k = lb512(s2s, -v1);
        float4 P0, P1, Q0, Q1;
        if (k > 0) {
            const float4* pp4 = (const float4*)&PP[k - 1][0];
            const float4* qq4 = (const float4*)&QQ[k - 1][0];
            P0 = pp4[0]; P1 = pp4[1]; Q0 = qq4[0]; Q1 = qq4[1];
        } else {
            P0 = P1 = Q0 = Q1 = make_float4(0.f, 0.f, 0.f, 0.f);
        }
        const float4 T0 = ((const float4*)&CTP[63][0])[0];
        const float4 T1 = ((const float4*)&CTP[63][0])[1];
        float h0 = p1 * (T0.x - P0.x) + q1 * Q0.x;
        float h1 = p1 * (T0.y - P0.y) + q1 * Q0.y;
        float h2 = p1 * (T0.z - P0.z) + q1 * Q0.z;
        float h3 = p1 * (T0.w - P0.w) + q1 * Q0.w;
        float h4 = p1 * (T1.x - P1.x) + q1 * Q1.x;
        float h5 = p1 * (T1.y - P1.y) + q1 * Q1.y;
        float h6 = p1 * (T1.z - P1.z) + q1 * Q1.z;
        float h7 = p1 * (T1.w - P1.w) + q1 * Q1.w;
        float* xp = x + ((size_t)(b * NN + t)) * (NHEADS * NHID) + h * NHID;
        ((float4*)xp)[0] = make_float4(elu1(h0), elu1(h1), elu1(h2), elu1(h3));
        ((float4*)xp)[1] = make_float4(elu1(h4), elu1(h5), elu1(h6), elu1(h7));
    }
}

// K34: per batch b — Wh2 = x@W_out, s1/s2; factorized den; row 0 only; elu; MLP head → out[b]
__global__ __launch_bounds__(512) void k34_tail(
        const float* __restrict__ x, const float* __restrict__ Wout,
        const float* __restrict__ aout, const float* __restrict__ feats,
        const float* __restrict__ l1w, const float* __restrict__ l1b,
        const float* __restrict__ pa, const float* __restrict__ gma,
        const float* __restrict__ bta, const float* __restrict__ l2w,
        const float* __restrict__ l2b, float* __restrict__ out)
{
    __shared__ __align__(16) float WL[64 * NHID];      // 2 KB
    __shared__ float aL[16];
    __shared__ __align__(16) float wh2[NN][NHID];      // 16 KB
    __shared__ __align__(16) float s1L[NN];
    __shared__ float s2L[NN], s1s[NN], prefP[NN], prefQ[NN];
    __shared__ __align__(16) float red[NN][NHID];      // 16 KB
    __shared__ float gatL[NHID];
    __shared__ float zL[NHID];

    const int b = blockIdx.x, t = threadIdx.x;
    if (t < 128) ((float4*)WL)[t] = ((const float4*)Wout)[t];
    if (t < 16) aL[t] = aout[t];
    __syncthreads();

    // Wh2 row t
    {
        float acc[NHID];
        #pragma unroll
        for (int d = 0; d < NHID; ++d) acc[d] = 0.f;
        const float4* row = (const float4*)(x + ((size_t)b * NN + t) * (NHEADS * NHID));
        #pragma unroll 4
        for (int k4 = 0; k4 < 16; ++k4) {
            float4 v = row[k4];
            const float* w0 = &WL[(k4 * 4 + 0) * NHID];
            const float* w1 = &WL[(k4 * 4 + 1) * NHID];
            const float* w2 = &WL[(k4 * 4 + 2) * NHID];
            const float* w3 = &WL[(k4 * 4 + 3) * NHID];
            #pragma unroll
            for (int d = 0; d < NHID; ++d)
                acc[d] += v.x * w0[d] + v.y * w1[d] + v.z * w2[d] + v.w * w3[d];
        }
        float a1 = 0.f, a2 = 0.f;
        #pragma unroll
        for (int d = 0; d < NHID; ++d) { a1 += acc[d] * aL[d]; a2 += acc[d] * aL[8 + d]; }
        float4* wr = (float4*)&wh2[t][0];
        wr[0] = make_float4(acc[0], acc[1], acc[2], acc[3]);
        wr[1] = make_float4(acc[4], acc[5], acc[6], acc[7]);
        s1L[t] = a1;
        s2L[t] = a2;
    }
    __syncthreads();

    // rank-count sort of s1
    const float v1 = s1L[t];
    int r1 = 0;
    {
        const float4* a4 = (const float4*)s1L;
        for (int k = 0; k < NN / 4; ++k) {
            float4 u = a4[k];
            const int i0 = k * 4;
            r1 += (u.x < v1) || (u.x == v1 && (i0 + 0) < t);
            r1 += (u.y < v1) || (u.y == v1 && (i0 + 1) < t);
            r1 += (u.z < v1) || (u.z == v1 && (i0 + 2) < t);
            r1 += (u.w < v1) || (u.w == v1 && (i0 + 3) < t);
        }
    }
    s1s[r1] = v1;
    __syncthreads();

    prefP[t] = __expf(s1s[t]);
    prefQ[t] = __expf(0.2f * s1s[t]);
    __syncthreads();
    for (int s = 1; s < NN; s <<= 1) {
        float ap = prefP[t], aq = prefQ[t];
        float bp = 0.f, bq = 0.f;
        if (t >= s) { bp = prefP[t - s]; bq = prefQ[t - s]; }
        __syncthreads();
        prefP[t] = ap + bp;
        prefQ[t] = aq + bq;
        __syncthreads();
    }

    // den for column t, weight of row 0, weighted Wh2 rows into red
    {
        const float TP = prefP[NN - 1];
        const float v2 = s2L[t];
        const int k = lb512(s1s, -v2);
        const float sp = TP - (k > 0 ? prefP[k - 1] : 0.f);
        const float sq = (k > 0 ? prefQ[k - 1] : 0.f);
        const float dj = __expf(v2) * sp + __expf(0.2f * v2) * sq;
        const float s10 = s1L[0];
        float e0 = s10 + v2;
        e0 = e0 >= 0.f ? e0 : LALPHA * e0;
        const float w0 = __expf(e0) / dj;
        #pragma unroll
        for (int d = 0; d < NHID; ++d) red[t][d] = w0 * wh2[t][d];
    }
    __syncthreads();
    for (int s = 256; s >= 1; s >>= 1) {
        if (t < s) {
            #pragma unroll
            for (int d = 0; d < NHID; ++d) red[t][d] += red[t + s][d];
        }
        __syncthreads();
    }
    if (t < NHID) gatL[t] = elu1(red[0][t]);
    __syncthreads();

    // head MLP
    if (t < NHID) {
        const float* w = l1w + t * (NFEAT + NHID);
        float z = l1b[t];
        for (int k = 0; k < NFEAT; ++k) z += feats[b * NFEAT + k] * w[k];
        #pragma unroll
        for (int k = 0; k < NHID; ++k) z += gatL[k] * w[NFEAT + k];
        const float a = pa[0];
        z = z >= 0.f ? z : a * z;
        z = z * (1.f / sqrtf(1.f + 1e-5f)) * gma[t] + bta[t];
        zL[t] = z;
    }
    __syncthreads();
    if (t == 0) {
        float o = l2b[0];
        #pragma unroll
        for (int d = 0; d < NHID; ++d) o += zL[d] * l2w[d];
        out[b] = o;
    }
}

extern "C" void kernel_launch(void* const* d_in, const int* in_sizes, int n_in,
                              void* d_out, int out_size, void* d_ws, size_t ws_size,
                              hipStream_t stream) {
    const float* feats = (const float*)d_in[0];
    const float* nf    = (const float*)d_in[1];
    const float* Ws    = (const float*)d_in[2];
    const float* As    = (const float*)d_in[3];
    const float* Wout  = (const float*)d_in[4];
    const float* aout  = (const float*)d_in[5];
    const float* l1w   = (const float*)d_in[6];
    const float* l1b   = (const float*)d_in[7];
    const float* pa    = (const float*)d_in[8];
    const float* gma   = (const float*)d_in[9];
    const float* bta   = (const float*)d_in[10];
    const float* l2w   = (const float*)d_in[11];
    const float* l2b   = (const float*)d_in[12];
    float* out = (float*)d_out;

    float* ws  = (float*)d_ws;
    float* Wh  = ws;                                    // 32*8*512*8 = 1048576
    float* s1  = Wh + (size_t)BB * NHEADS * NN * NHID;  // 131072
    float* s2  = s1 + (size_t)BB * NHEADS * NN;         // 131072
    float* x   = s2 + (size_t)BB * NHEADS * NN;         // 32*512*64 = 1048576

    k1_wh   <<<BB * NHEADS, 256, 0, stream>>>(nf, Ws, As, Wh, s1, s2);
    k2_attn1<<<BB * NHEADS, 512, 0, stream>>>(Wh, s1, s2, x);
    k34_tail<<<BB, 512, 0, stream>>>(x, Wout, aout, feats, l1w, l1b, pa, gma, bta, l2w, l2b, out);
}

// Round 3
// 56.617 us; speedup vs baseline: 2.6218x; 1.4135x over previous
//
#include <hip/hip_runtime.h>
#include <math.h>

#define BB 32
#define NN 512
#define NFEAT 128
#define NHID 8
#define NHEADS 8
#define LALPHA 0.2f

__device__ __forceinline__ float elu1(float x)  { return x > 0.f ? x : __expf(x) - 1.f; }

// monotone float -> uint mapping (total order refines float order)
__device__ __forceinline__ unsigned ordkey(float v) {
    unsigned u = __float_as_uint(v);
    return u ^ (((unsigned)((int)u >> 31)) | 0x80000000u);
}

// first index k in [0,512] with a[k] >= v (a ascending)
__device__ __forceinline__ int lb512(const float* a, float v) {
    int lo = 0, hi = NN;
    while (lo < hi) {
        int m = (lo + hi) >> 1;
        if (a[m] < v) lo = m + 1; else hi = m;
    }
    return lo;
}

// inclusive wave(64) scan
__device__ __forceinline__ float wscan(float x, int lane) {
    #pragma unroll
    for (int s = 1; s < 64; s <<= 1) {
        float y = __shfl_up(x, (unsigned)s, 64);
        x += (lane >= s) ? y : 0.f;
    }
    return x;
}

// Fused layer-1: Wh/s1/s2 in LDS, factorized attention via sorted prefix sums.
__global__ __launch_bounds__(512) void k12_gat1(
        const float* __restrict__ nf, const float* __restrict__ Ws,
        const float* __restrict__ As, float* __restrict__ x)
{
    __shared__ __align__(16) float WsL[NFEAT * NHID];          // 4 KB
    __shared__ float aL[16];
    __shared__ __align__(16) float whL[NN][NHID];              // 16 KB
    __shared__ __align__(16) float s1L[NN];
    __shared__ __align__(16) float s2L[NN];
    __shared__ __align__(16) unsigned long long key1[NN];      // 4 KB
    __shared__ __align__(16) unsigned long long key2[NN];      // 4 KB
    __shared__ float s1s[NN], s2s[NN];
    __shared__ int   idx2[NN];
    __shared__ float prefP[NN], prefQ[NN];
    __shared__ float den[NN];
    __shared__ __align__(16) float PP[NN][NHID];               // 16 KB
    __shared__ __align__(16) float QQ[NN][NHID];               // 16 KB
    __shared__ float wT[8][16];

    const int bh = blockIdx.x, b = bh >> 3, h = bh & 7;
    const int t = threadIdx.x;
    const int lane = t & 63, w = t >> 6;

    if (t < 256) ((float4*)WsL)[t] = ((const float4*)(Ws + (size_t)h * NFEAT * NHID))[t];
    if (t < 16) aL[t] = As[h * 16 + t];
    __syncthreads();

    // ---- Wh row t, s1, s2 ----
    float v1, v2;
    {
        const float4* row = (const float4*)(nf + ((size_t)b * NN + t) * NFEAT);
        float acc[NHID];
        #pragma unroll
        for (int d = 0; d < NHID; ++d) acc[d] = 0.f;
        #pragma unroll 8
        for (int f4 = 0; f4 < NFEAT / 4; ++f4) {
            float4 v = row[f4];
            const float* w0 = &WsL[(f4 * 4 + 0) * NHID];
            const float* w1 = &WsL[(f4 * 4 + 1) * NHID];
            const float* w2 = &WsL[(f4 * 4 + 2) * NHID];
            const float* w3 = &WsL[(f4 * 4 + 3) * NHID];
            #pragma unroll
            for (int d = 0; d < NHID; ++d)
                acc[d] += v.x * w0[d] + v.y * w1[d] + v.z * w2[d] + v.w * w3[d];
        }
        float a1 = 0.f, a2 = 0.f;
        #pragma unroll
        for (int d = 0; d < NHID; ++d) { a1 += acc[d] * aL[d]; a2 += acc[d] * aL[8 + d]; }
        v1 = a1; v2 = a2;
        float4* wr = (float4*)&whL[t][0];
        wr[0] = make_float4(acc[0], acc[1], acc[2], acc[3]);
        wr[1] = make_float4(acc[4], acc[5], acc[6], acc[7]);
        s1L[t] = v1;
        s2L[t] = v2;
        key1[t] = (((unsigned long long)ordkey(v1)) << 9) | (unsigned)t;
        key2[t] = (((unsigned long long)ordkey(v2)) << 9) | (unsigned)t;
    }
    __syncthreads();

    // ---- rank-count sort (u64 keys, exact + unique) ----
    {
        const unsigned long long m1 = key1[t], m2 = key2[t];
        int r1 = 0, r2 = 0;
        const ulonglong2* k1p = (const ulonglong2*)key1;
        const ulonglong2* k2p = (const ulonglong2*)key2;
        #pragma unroll 4
        for (int k = 0; k < NN / 2; ++k) {
            ulonglong2 u1 = k1p[k];
            ulonglong2 u2 = k2p[k];
            r1 += (u1.x < m1) + (u1.y < m1);
            r2 += (u2.x < m2) + (u2.y < m2);
        }
        s1s[r1] = v1;
        s2s[r2] = v2;
        idx2[r2] = t;
    }
    __syncthreads();

    // ---- scan exp over sorted s1 (wave scan + cross-wave offsets) ----
    float TP;
    {
        float p = __expf(s1s[t]);
        float q = __expf(0.2f * s1s[t]);
        float ps = wscan(p, lane);
        float qs = wscan(q, lane);
        if (lane == 63) { wT[w][0] = ps; wT[w][1] = qs; }
        __syncthreads();
        float offp = 0.f, offq = 0.f, totp = 0.f;
        #pragma unroll
        for (int ww = 0; ww < 8; ++ww) {
            float tp = wT[ww][0], tq = wT[ww][1];
            totp += tp;
            if (ww < w) { offp += tp; offq += tq; }
        }
        prefP[t] = ps + offp;
        prefQ[t] = qs + offq;
        TP = totp;
    }
    __syncthreads();

    // ---- den for column j = t ----
    {
        const int k = lb512(s1s, -v2);
        float pk = 0.f, qk = 0.f;
        if (k > 0) { pk = prefP[k - 1]; qk = prefQ[k - 1]; }
        den[t] = __expf(v2) * (TP - pk) + __expf(0.2f * v2) * qk;
    }
    __syncthreads();

    // ---- payload at sorted s2 position t; scan 16 components ----
    float pv[NHID], qv[NHID];
    {
        const int j = idx2[t];
        const float key = s2s[t];
        const float invd = 1.f / den[j];
        const float4 w0 = ((const float4*)&whL[j][0])[0];
        const float4 w1 = ((const float4*)&whL[j][0])[1];
        const float pw = __expf(key) * invd;
        const float qw = __expf(0.2f * key) * invd;
        pv[0] = pw * w0.x; pv[1] = pw * w0.y; pv[2] = pw * w0.z; pv[3] = pw * w0.w;
        pv[4] = pw * w1.x; pv[5] = pw * w1.y; pv[6] = pw * w1.z; pv[7] = pw * w1.w;
        qv[0] = qw * w0.x; qv[1] = qw * w0.y; qv[2] = qw * w0.z; qv[3] = qw * w0.w;
        qv[4] = qw * w1.x; qv[5] = qw * w1.y; qv[6] = qw * w1.z; qv[7] = qw * w1.w;
    }
    #pragma unroll
    for (int c = 0; c < NHID; ++c) {
        pv[c] = wscan(pv[c], lane);
        qv[c] = wscan(qv[c], lane);
    }
    if (lane == 63) {
        #pragma unroll
        for (int c = 0; c < NHID; ++c) { wT[w][c] = pv[c]; wT[w][8 + c] = qv[c]; }
    }
    __syncthreads();
    float totP[NHID];
    {
        float offP[NHID], offQ[NHID];
        #pragma unroll
        for (int c = 0; c < NHID; ++c) { offP[c] = 0.f; offQ[c] = 0.f; totP[c] = 0.f; }
        #pragma unroll
        for (int ww = 0; ww < 8; ++ww) {
            #pragma unroll
            for (int c = 0; c < NHID; ++c) {
                float tp = wT[ww][c], tq = wT[ww][8 + c];
                totP[c] += tp;
                if (ww < w) { offP[c] += tp; offQ[c] += tq; }
            }
        }
        #pragma unroll
        for (int c = 0; c < NHID; ++c) { pv[c] += offP[c]; qv[c] += offQ[c]; }
        float4* pp = (float4*)&PP[t][0];
        float4* qq = (float4*)&QQ[t][0];
        pp[0] = make_float4(pv[0], pv[1], pv[2], pv[3]);
        pp[1] = make_float4(pv[4], pv[5], pv[6], pv[7]);
        qq[0] = make_float4(qv[0], qv[1], qv[2], qv[3]);
        qq[1] = make_float4(qv[4], qv[5], qv[6], qv[7]);
    }
    __syncthreads();

    // ---- row i = t ----
    {
        const float p1 = __expf(v1), q1 = __expf(0.2f * v1);
        const int k = lb512(s2s, -v1);
        float4 P0, P1, Q0, Q1;
        if (k > 0) {
            const float4* pp4 = (const float4*)&PP[k - 1][0];
            const float4* qq4 = (const float4*)&QQ[k - 1][0];
            P0 = pp4[0]; P1 = pp4[1]; Q0 = qq4[0]; Q1 = qq4[1];
        } else {
            P0 = P1 = Q0 = Q1 = make_float4(0.f, 0.f, 0.f, 0.f);
        }
        float h0 = p1 * (totP[0] - P0.x) + q1 * Q0.x;
        float h1 = p1 * (totP[1] - P0.y) + q1 * Q0.y;
        float h2 = p1 * (totP[2] - P0.z) + q1 * Q0.z;
        float h3 = p1 * (totP[3] - P0.w) + q1 * Q0.w;
        float h4 = p1 * (totP[4] - P1.x) + q1 * Q1.x;
        float h5 = p1 * (totP[5] - P1.y) + q1 * Q1.y;
        float h6 = p1 * (totP[6] - P1.z) + q1 * Q1.z;
        float h7 = p1 * (totP[7] - P1.w) + q1 * Q1.w;
        float* xp = x + ((size_t)(b * NN + t)) * (NHEADS * NHID) + h * NHID;
        ((float4*)xp)[0] = make_float4(elu1(h0), elu1(h1), elu1(h2), elu1(h3));
        ((float4*)xp)[1] = make_float4(elu1(h4), elu1(h5), elu1(h6), elu1(h7));
    }
}

// Tail per batch b: Wh2 = x@W_out, factorized dens, row-0 attention, elu, MLP head.
__global__ __launch_bounds__(512) void k34_tail(
        const float* __restrict__ x, const float* __restrict__ Wout,
        const float* __restrict__ aout, const float* __restrict__ feats,
        const float* __restrict__ l1w, const float* __restrict__ l1b,
        const float* __restrict__ pa, const float* __restrict__ gma,
        const float* __restrict__ bta, const float* __restrict__ l2w,
        const float* __restrict__ l2b, float* __restrict__ out)
{
    __shared__ __align__(16) float WL[64 * NHID];              // 2 KB
    __shared__ float aL[16];
    __shared__ __align__(16) float wh2[NN][NHID];              // 16 KB
    __shared__ __align__(16) float s1L[NN];
    __shared__ float s2L[NN];
    __shared__ __align__(16) unsigned long long key1[NN];      // 4 KB
    __shared__ float s1s[NN], prefP[NN], prefQ[NN];
    __shared__ float wT[8][2];
    __shared__ float wR[8][NHID];
    __shared__ float gatL[NHID];
    __shared__ float zL[NHID];

    const int b = blockIdx.x, t = threadIdx.x;
    const int lane = t & 63, w = t >> 6;

    if (t < 128) ((float4*)WL)[t] = ((const float4*)Wout)[t];
    if (t < 16) aL[t] = aout[t];
    __syncthreads();

    // Wh2 row t
    float v1, v2;
    {
        float acc[NHID];
        #pragma unroll
        for (int d = 0; d < NHID; ++d) acc[d] = 0.f;
        const float4* row = (const float4*)(x + ((size_t)b * NN + t) * (NHEADS * NHID));
        #pragma unroll 4
        for (int k4 = 0; k4 < 16; ++k4) {
            float4 v = row[k4];
            const float* w0 = &WL[(k4 * 4 + 0) * NHID];
            const float* w1 = &WL[(k4 * 4 + 1) * NHID];
            const float* w2 = &WL[(k4 * 4 + 2) * NHID];
            const float* w3 = &WL[(k4 * 4 + 3) * NHID];
            #pragma unroll
            for (int d = 0; d < NHID; ++d)
                acc[d] += v.x * w0[d] + v.y * w1[d] + v.z * w2[d] + v.w * w3[d];
        }
        float a1 = 0.f, a2 = 0.f;
        #pragma unroll
        for (int d = 0; d < NHID; ++d) { a1 += acc[d] * aL[d]; a2 += acc[d] * aL[8 + d]; }
        v1 = a1; v2 = a2;
        float4* wr = (float4*)&wh2[t][0];
        wr[0] = make_float4(acc[0], acc[1], acc[2], acc[3]);
        wr[1] = make_float4(acc[4], acc[5], acc[6], acc[7]);
        s1L[t] = v1;
        s2L[t] = v2;
        key1[t] = (((unsigned long long)ordkey(v1)) << 9) | (unsigned)t;
    }
    __syncthreads();

    // rank-count sort of s1
    {
        const unsigned long long m1 = key1[t];
        int r1 = 0;
        const ulonglong2* k1p = (const ulonglong2*)key1;
        #pragma unroll 4
        for (int k = 0; k < NN / 2; ++k) {
            ulonglong2 u = k1p[k];
            r1 += (u.x < m1) + (u.y < m1);
        }
        s1s[r1] = v1;
    }
    __syncthreads();

    // scans of exp over sorted s1
    float TP;
    {
        float p = __expf(s1s[t]);
        float q = __expf(0.2f * s1s[t]);
        float ps = wscan(p, lane);
        float qs = wscan(q, lane);
        if (lane == 63) { wT[w][0] = ps; wT[w][1] = qs; }
        __syncthreads();
        float offp = 0.f, offq = 0.f, totp = 0.f;
        #pragma unroll
        for (int ww = 0; ww < 8; ++ww) {
            float tp = wT[ww][0], tq = wT[ww][1];
            totp += tp;
            if (ww < w) { offp += tp; offq += tq; }
        }
        prefP[t] = ps + offp;
        prefQ[t] = qs + offq;
        TP = totp;
    }
    __syncthreads();

    // den for column t, weight of row 0, weighted reduce of wh2 rows
    float acc[NHID];
    {
        const int k = lb512(s1s, -v2);
        const float pk = (k > 0) ? prefP[k - 1] : 0.f;
        const float qk = (k > 0) ? prefQ[k - 1] : 0.f;
        const float dj = __expf(v2) * (TP - pk) + __expf(0.2f * v2) * qk;
        const float s10 = s1L[0];
        float e0 = s10 + v2;
        e0 = e0 >= 0.f ? e0 : LALPHA * e0;
        const float wgt = __expf(e0) / dj;
        #pragma unroll
        for (int d = 0; d < NHID; ++d) acc[d] = wgt * wh2[t][d];
    }
    #pragma unroll
    for (int s = 1; s < 64; s <<= 1) {
        #pragma unroll
        for (int d = 0; d < NHID; ++d) acc[d] += __shfl_xor(acc[d], s, 64);
    }
    if (lane == 0) {
        #pragma unroll
        for (int d = 0; d < NHID; ++d) wR[w][d] = acc[d];
    }
    __syncthreads();
    if (t < NHID) {
        float g = 0.f;
        #pragma unroll
        for (int ww = 0; ww < 8; ++ww) g += wR[ww][t];
        gatL[t] = elu1(g);
    }
    __syncthreads();

    // head MLP
    if (t < NHID) {
        const float* wv = l1w + t * (NFEAT + NHID);
        float z = l1b[t];
        for (int k = 0; k < NFEAT; ++k) z += feats[b * NFEAT + k] * wv[k];
        #pragma unroll
        for (int k = 0; k < NHID; ++k) z += gatL[k] * wv[NFEAT + k];
        const float a = pa[0];
        z = z >= 0.f ? z : a * z;
        z = z * (1.f / sqrtf(1.f + 1e-5f)) * gma[t] + bta[t];
        zL[t] = z;
    }
    __syncthreads();
    if (t == 0) {
        float o = l2b[0];
        #pragma unroll
        for (int d = 0; d < NHID; ++d) o += zL[d] * l2w[d];
        out[b] = o;
    }
}

extern "C" void kernel_launch(void* const* d_in, const int* in_sizes, int n_in,
                              void* d_out, int out_size, void* d_ws, size_t ws_size,
                              hipStream_t stream) {
    const float* feats = (const float*)d_in[0];
    const float* nf    = (const float*)d_in[1];
    const float* Ws    = (const float*)d_in[2];
    const float* As    = (const float*)d_in[3];
    const float* Wout  = (const float*)d_in[4];
    const float* aout  = (const float*)d_in[5];
    const float* l1w   = (const float*)d_in[6];
    const float* l1b   = (const float*)d_in[7];
    const float* pa    = (const float*)d_in[8];
    const float* gma   = (const float*)d_in[9];
    const float* bta   = (const float*)d_in[10];
    const float* l2w   = (const float*)d_in[11];
    const float* l2b   = (const float*)d_in[12];
    float* out = (float*)d_out;

    float* x = (float*)d_ws;   // 32*512*64 floats = 4 MB

    k12_gat1<<<BB * NHEADS, 512, 0, stream>>>(nf, Ws, As, x);
    k34_tail<<<BB, 512, 0, stream>>>(x, Wout, aout, feats, l1w, l1b, pa, gma, bta, l2w, l2b, out);
}